// Round 20
// baseline (150.430 us; speedup 1.0000x reference)
//
#include <hip/hip_runtime.h>

#define HIDD 1024
#define NHH  16
#define HDD  64
#define BBB  2
#define SSS  2048
#define BS   (BBB * SSS)   // 4096

typedef __attribute__((ext_vector_type(8))) _Float16 half8;
typedef __attribute__((ext_vector_type(4))) _Float16 half4;
typedef __attribute__((ext_vector_type(4))) float    f32x4;

#define LSCALE 2048.0f        // 2^11: pre-scale for fp16 low part
#define LINV   (1.0f / 2048.0f)

static __device__ __forceinline__ f32x4 mfma16h(half8 a, half8 b, f32x4 c) {
    return __builtin_amdgcn_mfma_f32_16x16x32_f16(a, b, c, 0, 0, 0);
}

// split2 fp16: v ~= h + l*2^-11, rep error ~2^-22 |v|
static __device__ __forceinline__ void split2h(float v, _Float16& h, _Float16& l) {
    h = (_Float16)v;
    l = (_Float16)((v - (float)h) * LSCALE);
}

// async global->LDS, 16B per lane; LDS dest = wave-uniform base + lane*16
static __device__ __forceinline__ void gl_lds16(const _Float16* g, _Float16* l) {
    __builtin_amdgcn_global_load_lds(
        (const __attribute__((address_space(1))) unsigned int*)g,
        (__attribute__((address_space(3))) unsigned int*)l,
        16, 0, 0);
}

// ---------- weight prep: W[n][d][e] f32 -> WT h/l fp16 [mat*16+n][e][d] --------------
__global__ __launch_bounds__(256) void k_wprep(const float* __restrict__ wq,
                                               const float* __restrict__ wk,
                                               const float* __restrict__ wv,
                                               _Float16* __restrict__ WTh,
                                               _Float16* __restrict__ WTl) {
    const int blk = blockIdx.x;            // mat*16 + n
    const int mat = blk >> 4, n = blk & 15;
    const float* src = (mat == 0 ? wq : mat == 1 ? wk : wv) + (size_t)n * 4096;
    for (int c = threadIdx.x; c < 4096; c += 256) {
        int e = c >> 6, d = c & 63;
        float v = src[d * 64 + e];
        _Float16 h, l;
        split2h(v, h, l);
        WTh[(size_t)blk * 4096 + c] = h;   // layout [e][d]
        WTl[(size_t)blk * 4096 + c] = l;
    }
}

// ------- per-head Q/K/V projection: 8 waves/128 rows, all 3 mats staged once ---------
// V^T is written PRE-PERMUTED per 64-t tile: slot s=32kf+8hi+j holds t=32kf+16(j>>2)+4hi+(j&3)
__global__ __launch_bounds__(512) void k_proj_mfma(const float* __restrict__ x,
                                                   const _Float16* __restrict__ WTh,
                                                   const _Float16* __restrict__ WTl,
                                                   _Float16* __restrict__ Qh, _Float16* __restrict__ Ql,
                                                   _Float16* __restrict__ Kh, _Float16* __restrict__ Kl,
                                                   _Float16* __restrict__ VTh, _Float16* __restrict__ VTl) {
    const int n  = blockIdx.y;
    const int R0 = blockIdx.x * 128;
    const int tid = threadIdx.x;
    const int w = tid >> 6, lane = tid & 63;
    const int hi = lane >> 4, lo = lane & 15;

    __shared__ __align__(16) _Float16 smem[27648];

    half8 ah[2], al[2];
#pragma unroll
    for (int kf = 0; kf < 2; kf++) {
        const float* xp = x + (size_t)(R0 + 16 * w + lo) * HIDD + n * HDD + kf * 32 + 8 * hi;
        float4 v0 = *(const float4*)xp;
        float4 v1 = *(const float4*)(xp + 4);
        float vv[8] = { v0.x, v0.y, v0.z, v0.w, v1.x, v1.y, v1.z, v1.w };
#pragma unroll
        for (int j = 0; j < 8; ++j) {
            _Float16 h, l;
            split2h(vv[j], h, l);
            ah[kf][j] = h; al[kf][j] = l;
        }
    }

    for (int c = tid; c < 3072; c += 512) {
        int m = c >> 10, rest = c & 1023, hl = rest >> 9, cc = rest & 511;
        int r = cc >> 3, j8 = (cc & 7) << 3;
        const _Float16* src = (hl ? WTl : WTh) + ((size_t)(m * NHH + n)) * 4096 + r * 64 + j8;
        *(half8*)&smem[(m * 2 + hl) * 4608 + r * 72 + j8] = *(const half8*)src;
    }
    __syncthreads();

    const int bq = R0 >> 11;
    const int sr = R0 & 2047;
    const size_t bn = (size_t)(bq * NHH + n);
    float vkeep[4][4][2];

    for (int mat = 0; mat < 3; ++mat) {
        const _Float16* bh_base = smem + (mat * 2 + 0) * 4608;
        const _Float16* bl_base = smem + (mat * 2 + 1) * 4608;
        f32x4 a0[4], a1[4];
#pragma unroll
        for (int eb = 0; eb < 4; ++eb) {
            a0[eb] = (f32x4){0.f, 0.f, 0.f, 0.f};
            a1[eb] = (f32x4){0.f, 0.f, 0.f, 0.f};
        }
#pragma unroll
        for (int eb = 0; eb < 4; ++eb) {
            half8 bh0 = *(const half8*)&bh_base[(16 * eb + lo) * 72 + 8 * hi];
            half8 bh1 = *(const half8*)&bh_base[(16 * eb + lo) * 72 + 32 + 8 * hi];
            half8 bl0 = *(const half8*)&bl_base[(16 * eb + lo) * 72 + 8 * hi];
            half8 bl1 = *(const half8*)&bl_base[(16 * eb + lo) * 72 + 32 + 8 * hi];
            a0[eb] = mfma16h(ah[0], bh0, a0[eb]);
            a0[eb] = mfma16h(ah[1], bh1, a0[eb]);
            a1[eb] = mfma16h(ah[0], bl0, a1[eb]);
            a1[eb] = mfma16h(al[0], bh0, a1[eb]);
            a1[eb] = mfma16h(ah[1], bl1, a1[eb]);
            a1[eb] = mfma16h(al[1], bh1, a1[eb]);
        }

        if (mat < 2) {
            _Float16* Dh = (mat == 0) ? Qh : Kh;
            _Float16* Dl = (mat == 0) ? Ql : Kl;
#pragma unroll
            for (int eb = 0; eb < 4; ++eb)
#pragma unroll
                for (int r = 0; r < 4; ++r) {
                    int gr = R0 + 16 * w + 4 * hi + r;
                    int s = gr & 2047;
                    float val = a0[eb][r] + a1[eb][r] * LINV;
                    _Float16 h, l;
                    split2h(val, h, l);
                    size_t idx = (bn * SSS + s) * HDD + 16 * eb + lo;
                    Dh[idx] = h; Dl[idx] = l;
                }
        } else {
#pragma unroll
            for (int eb = 0; eb < 4; ++eb)
#pragma unroll
                for (int r = 0; r < 4; ++r) {
                    vkeep[eb][r][0] = a0[eb][r];
                    vkeep[eb][r][1] = a1[eb][r];
                }
        }
    }

    __syncthreads();
    _Float16* tbh = smem;
    _Float16* tbl = smem + 8704;
#pragma unroll
    for (int eb = 0; eb < 4; ++eb)
#pragma unroll
        for (int r = 0; r < 4; ++r) {
            int rl = 16 * w + 4 * hi + r;
            int ch = 16 * eb + lo;
            _Float16 h, l;
            split2h(vkeep[eb][r][0] + vkeep[eb][r][1] * LINV, h, l);
            tbh[ch * 136 + rl] = h;
            tbl[ch * 136 + rl] = l;
        }
    __syncthreads();
    // permuted writeout: dest slot s (within 64-tile) <- src t = a64 + 32kf + 16(j>>2) + 4hi + (j&3)
    for (int c = tid; c < 1024; c += 512) {
        int ch = c >> 4, s8 = (c & 15) << 3;
        int a64 = s8 & 64;
        int s0 = s8 & 63;                              // 32kf + 8hi
        int basePerm = a64 + (s0 & 32) + ((s0 >> 3) & 3) * 4;   // a64 + 32kf + 4hi
        const _Float16* th = &tbh[ch * 136];
        const _Float16* tl = &tbl[ch * 136];
        half4 h0 = *(const half4*)(th + basePerm);
        half4 h1 = *(const half4*)(th + basePerm + 16);
        half4 l0 = *(const half4*)(tl + basePerm);
        half4 l1 = *(const half4*)(tl + basePerm + 16);
        half8 oh = {h0[0], h0[1], h0[2], h0[3], h1[0], h1[1], h1[2], h1[3]};
        half8 ol = {l0[0], l0[1], l0[2], l0[3], l1[0], l1[1], l1[2], l1[3]};
        size_t gi = (bn * HDD + ch) * SSS + sr + s8;
        *(half8*)(VTh + gi) = oh;
        *(half8*)(VTl + gi) = ol;
    }
}

// ---- retention: persistent + work-stealing + T4 COUNTED-VMCNT 3-phase pipeline ------
__global__ __launch_bounds__(256) void k_ret_mfma(const _Float16* __restrict__ Qh, const _Float16* __restrict__ Ql,
                                                  const _Float16* __restrict__ Kh, const _Float16* __restrict__ Kl,
                                                  const _Float16* __restrict__ VTh, const _Float16* __restrict__ VTl,
                                                  const float* __restrict__ gns,
                                                  const float* __restrict__ gnb,
                                                  float* __restrict__ normb,
                                                  unsigned* __restrict__ counter) {
    const int tid = threadIdx.x;
    const int w = tid >> 6, lane = tid & 63;
    const int hi = lane >> 4, lo = lane & 15;

    // 3-phase sub-tile LDS (linear; swizzle folded into global src): 4 arrays x 12 KB
    __shared__ __align__(16) _Float16 ksh[3 * 2048];
    __shared__ __align__(16) _Float16 ksl[3 * 2048];
    __shared__ __align__(16) _Float16 vsh[3 * 2048];
    __shared__ __align__(16) _Float16 vsl[3 * 2048];
    __shared__ unsigned sitem;

    // lane-constant pieces independent of the work item
    const int ks0 = ((hi ^ (lo & 7)) << 3);
    const int ks1 = (((4 + hi) ^ (lo & 7)) << 3);
    const int vs0 = ((hi ^ ((lo >> 1) & 3)) << 3);
    size_t goffK = (size_t)(lane >> 3) * HDD + (size_t)((((lane & 7) ^ ((lane >> 3) & 7))) << 3);
    size_t goffV = (size_t)(lane >> 2) * SSS + (size_t)((((lane & 3) ^ ((lane >> 3) & 3))) << 3);

    const double l512 = -6.2383246250395075;   // log(1/512)
    const double l32  = -3.4657359027997265;   // log(1/32)

    while (true) {
        if (tid == 0) sitem = atomicAdd(counter, 1u);
        __syncthreads();
        const unsigned it = sitem;
        __syncthreads();
        if (it >= 1024u) break;

        // heavy-first decode: qt descending (LPT greedy)
        const int qt = 31 - (int)(it >> 5);
        const int n  = (int)(it & 15);
        const int b  = (int)((it >> 4) & 1);

        double lin = l512 + (double)n * (l32 - l512) / 15.0;
        float gamma = (float)(1.0 - exp(lin));
        float l2g = log2f(gamma);                  // negative
        int dmax = (int)(16.0f / (-l2g)) + 1;      // keep gamma^d >= 2^-16

        const int qb = qt * 64;
        const int qw = qb + 16 * w;
        int stb_start = (qb > dmax) ? ((qb - dmax) >> 5) : 0;
        const int stb_end  = 2 * qt + 1;
        const int stb_diag = qw >> 5;

        const size_t bn = (size_t)(b * NHH + n);
        const _Float16* Qhp = Qh + bn * SSS * HDD;
        const _Float16* Qlp = Ql + bn * SSS * HDD;
        const _Float16* Khp = Kh + bn * SSS * HDD;
        const _Float16* Klp = Kl + bn * SSS * HDD;
        const _Float16* Vhp = VTh + bn * HDD * SSS;
        const _Float16* Vlp = VTl + bn * HDD * SSS;

        half8 qfh[2], qfl[2];
#pragma unroll
        for (int kf = 0; kf < 2; kf++) {
            size_t o = (size_t)(qw + lo) * HDD + kf * 32 + 8 * hi;
            qfh[kf] = *(const half8*)(Qhp + o);
            qfl[kf] = *(const half8*)(Qlp + o);
        }

        f32x4 acc0[4], acc1[4];
#pragma unroll
        for (int e = 0; e < 4; e++) {
            acc0[e] = (f32x4){0.f, 0.f, 0.f, 0.f};
            acc1[e] = (f32x4){0.f, 0.f, 0.f, 0.f};
        }

        const _Float16* sg = (w == 0) ? Khp : (w == 1) ? Klp : (w == 2) ? Vhp : Vlp;
        _Float16* slds = (w == 0) ? ksh : (w == 1) ? ksl : (w == 2) ? vsh : vsl;
        const size_t goff = (w < 2) ? goffK : goffV;

        auto issue = [&](int tbase, int pbuf) {
            _Float16* Lb = slds + pbuf * 2048;
            if (w < 2) {
#pragma unroll
                for (int i = 0; i < 4; ++i)
                    gl_lds16(sg + (size_t)(tbase + 8 * i) * HDD + goff, Lb + i * 512);
            } else {
#pragma unroll
                for (int i = 0; i < 4; ++i)
                    gl_lds16(sg + (size_t)(16 * i) * SSS + tbase + goff, Lb + i * 512);
            }
        };

        float ftile = exp2f((float)(qw + lo - stb_start * 32) * l2g);
        const float gi16   = exp2f(-16.0f * l2g);
        const float ginv32 = exp2f(-32.0f * l2g);
        float f4[4];
#pragma unroll
        for (int r = 0; r < 4; ++r) f4[r] = exp2f(-(float)(4 * hi + r) * l2g);

        // ---- prologue: 2 sub-tiles in flight (4 loads each per wave) ----
        issue(stb_start * 32, 0);
        if (stb_start < stb_end) issue(stb_start * 32 + 32, 1);

        for (int stb = stb_start; stb <= stb_end; ++stb) {
            const int ph = (stb - stb_start) % 3;
            const int tbase = stb * 32;

            // T4: wait own current-subtile loads only (never drain mid-loop)
            if (stb < stb_end) asm volatile("s_waitcnt vmcnt(4)" ::: "memory");
            else               asm volatile("s_waitcnt vmcnt(0)" ::: "memory");
            __builtin_amdgcn_s_barrier();
            __builtin_amdgcn_sched_barrier(0);

            if (stb + 2 <= stb_end) issue(tbase + 64, (ph + 2) % 3);  // 2-ahead prefetch

            const bool active = (tbase <= qw + 15) && (tbase + 31 >= qw - dmax);
            if (active) {
                const bool dm = (stb == stb_diag);
                const _Float16* kh_ = &ksh[ph * 2048];
                const _Float16* kl_ = &ksl[ph * 2048];
                const _Float16* vh_ = &vsh[ph * 2048];
                const _Float16* vl_ = &vsl[ph * 2048];
                _Float16 ph4[2][4], pl4[2][4];
#pragma unroll
                for (int tt = 0; tt < 2; ++tt) {
                    int rb = (16 * tt + lo) * 64;
                    half8 kh0 = *(const half8*)&kh_[rb + ks0];
                    half8 kh1 = *(const half8*)&kh_[rb + ks1];
                    half8 kl0 = *(const half8*)&kl_[rb + ks0];
                    half8 kl1 = *(const half8*)&kl_[rb + ks1];
                    f32x4 s0 = (f32x4){0.f, 0.f, 0.f, 0.f};
                    f32x4 s1 = (f32x4){0.f, 0.f, 0.f, 0.f};
                    s0 = mfma16h(kh0, qfh[0], s0);
                    s0 = mfma16h(kh1, qfh[1], s0);
                    s1 = mfma16h(kl0, qfh[0], s1);
                    s1 = mfma16h(kh0, qfl[0], s1);
                    s1 = mfma16h(kl1, qfh[1], s1);
                    s1 = mfma16h(kh1, qfl[1], s1);
                    const float g = tt ? ftile * gi16 : ftile;
#pragma unroll
                    for (int r = 0; r < 4; r++) {
                        float p = (s0[r] + s1[r] * LINV) * (g * f4[r]);
                        if (dm) {
                            int diff = (qw + lo) - (tbase + 16 * tt + 4 * hi + r);
                            if (diff < 0) p = 0.0f;
                        }
                        split2h(p, ph4[tt][r], pl4[tt][r]);
                    }
                }
                half8 pfh = (half8){ph4[0][0], ph4[0][1], ph4[0][2], ph4[0][3],
                                    ph4[1][0], ph4[1][1], ph4[1][2], ph4[1][3]};
                half8 pfl = (half8){pl4[0][0], pl4[0][1], pl4[0][2], pl4[0][3],
                                    pl4[1][0], pl4[1][1], pl4[1][2], pl4[1][3]};
#pragma unroll
                for (int e = 0; e < 4; e++) {
                    int vb = (16 * e + lo) * 32 + vs0;
                    half8 vh0 = *(const half8*)&vh_[vb];
                    half8 vl0 = *(const half8*)&vl_[vb];
                    acc0[e] = mfma16h(pfh, vh0, acc0[e]);
                    acc1[e] = mfma16h(pfh, vl0, acc1[e]);
                    acc1[e] = mfma16h(pfl, vh0, acc1[e]);
                }
            }
            ftile *= ginv32;
        }

        // combine scaled-low accumulator
        f32x4 accf[4];
#pragma unroll
        for (int e = 0; e < 4; e++)
#pragma unroll
            for (int r = 0; r < 4; r++)
                accf[e][r] = acc0[e][r] + acc1[e][r] * LINV;

        // ---- fused GroupNorm (row=4hi+r -> q, col=lo -> ch; VERIFIED) ----
        float s[4], sq[4];
#pragma unroll
        for (int r = 0; r < 4; r++) {
            s[r] = 0.f; sq[r] = 0.f;
#pragma unroll
            for (int e = 0; e < 4; e++) { float v = accf[e][r]; s[r] += v; sq[r] += v * v; }
        }
#pragma unroll
        for (int mask = 1; mask < 16; mask <<= 1)
#pragma unroll
            for (int r = 0; r < 4; r++) {
                s[r]  += __shfl_xor(s[r],  mask);
                sq[r] += __shfl_xor(sq[r], mask);
            }
#pragma unroll
        for (int e = 0; e < 4; e++)
#pragma unroll
            for (int r = 0; r < 4; r++) {
                float mean = s[r] * (1.0f / 64.0f);
                float var  = sq[r] * (1.0f / 64.0f) - mean * mean;
                float rstd = rsqrtf(var + 1e-5f);
                int ch = 16 * e + lo;
                int sg2 = qw + 4 * hi + r;
                float nv = (accf[e][r] - mean) * rstd;
                nv = nv * gns[n * 64 + ch] + gnb[n * 64 + ch];
                normb[((size_t)b * SSS + sg2) * HIDD + n * 64 + ch] = nv;
            }
        __syncthreads();   // all waves done before next item reuses LDS
    }
}

// ---------------- f32 -> fp16 cast ----------------
__global__ __launch_bounds__(256) void k_cvt_h(const float* __restrict__ src,
                                               _Float16* __restrict__ dst) {
    int i = blockIdx.x * 256 + threadIdx.x;
    float4 v = reinterpret_cast<const float4*>(src)[i];
    half4 o = { (_Float16)v.x, (_Float16)v.y, (_Float16)v.z, (_Float16)v.w };
    reinterpret_cast<half4*>(dst)[i] = o;
}

// ------------- transpose f32 [K][N] -> fp16 [N][K] -------------
__global__ __launch_bounds__(256) void k_tr_h(const float* __restrict__ src,
                                              _Float16* __restrict__ dst,
                                              int K, int N) {
    __shared__ float ls[32][33];
    int kb = blockIdx.y * 32, nb = blockIdx.x * 32;
    int tx = threadIdx.x & 31, ty = threadIdx.x >> 5;   // 32 x 8
#pragma unroll
    for (int i = 0; i < 4; i++) {
        int r = ty + 8 * i;
        ls[r][tx] = src[(size_t)(kb + r) * N + nb + tx];
    }
    __syncthreads();
#pragma unroll
    for (int i = 0; i < 4; i++) {
        int r = ty + 8 * i;
        dst[(size_t)(nb + r) * K + kb + tx] = (_Float16)ls[tx][r];
    }
}

// ------- 128x128 fp16 MFMA GEMM, DOUBLE-BUFFERED global_load_lds, BK=64 --------------
template <int MODE>
__global__ __launch_bounds__(256) void k_gemm_h(const _Float16* __restrict__ A,
                                                const _Float16* __restrict__ Bt,
                                                const float* __restrict__ normb,
                                                _Float16* __restrict__ Y,
                                                float* __restrict__ Out) {
    const int Rb = blockIdx.x * 128, Cb = blockIdx.y * 128;
    const int tid = threadIdx.x, w = tid >> 6, lane = tid & 63;
    const int hi = lane >> 4, lo = lane & 15;
    const int wm = w >> 1, wn = w & 1;

    __shared__ __align__(16) _Float16 as[2][128 * 64];   // 2 x 16 KB
    __shared__ __align__(16) _Float16 bs[2][128 * 64];   // 2 x 16 KB

    f32x4 acc[4][4];
#pragma unroll
    for (int m = 0; m < 4; m++)
#pragma unroll
        for (int nn = 0; nn < 4; nn++) acc[m][nn] = (f32x4){0.f, 0.f, 0.f, 0.f};

    const _Float16* gM = (w < 2) ? (A + (size_t)(Rb + 64 * (w & 1)) * HIDD)
                                 : (Bt + (size_t)(Cb + 64 * (w & 1)) * HIDD);
    const int wsel = (w < 2) ? 0 : 1;     // 0 -> as, 1 -> bs
    const size_t gofs = (size_t)(lane >> 3) * HIDD
                      + (size_t)((((lane & 7) ^ ((lane >> 3) & 7))) << 3);

    auto issue = [&](int kk, int pbuf) {
        _Float16* gL = (wsel ? bs[pbuf] : as[pbuf]) + (w & 1) * 64 * 64;
#pragma unroll
        for (int i = 0; i < 8; ++i)
            gl_lds16(gM + (size_t)(8 * i) * HIDD + kk * 64 + gofs, gL + i * 512);
    };

    int rsw[2];
#pragma unroll
    for (int kf = 0; kf < 2; kf++) rsw[kf] = ((4 * kf + hi) ^ (lo & 7)) << 3;

    int pb = 0;
    issue(0, 0);
    __syncthreads();

    for (int kk = 0; kk < 16; ++kk) {
        if (kk < 15) issue(kk + 1, pb ^ 1);     // async loads overlap MFMA below

        half8 af[4][2], bf[4][2];
#pragma unroll
        for (int m = 0; m < 4; m++) {
            int row = 64 * wm + 16 * m + lo;
#pragma unroll
            for (int kf = 0; kf < 2; kf++)
                af[m][kf] = *(const half8*)&as[pb][row * 64 + rsw[kf]];
        }
#pragma unroll
        for (int nn = 0; nn < 4; nn++) {
            int row = 64 * wn + 16 * nn + lo;
#pragma unroll
            for (int kf = 0; kf < 2; kf++)
                bf[nn][kf] = *(const half8*)&bs[pb][row * 64 + rsw[kf]];
        }
#pragma unroll
        for (int m = 0; m < 4; m++)
#pragma unroll
            for (int nn = 0; nn < 4; nn++) {
                acc[m][nn] = mfma16h(af[m][0], bf[nn][0], acc[m][nn]);
                acc[m][nn] = mfma16h(af[m][1], bf[nn][1], acc[m][nn]);
            }
        __syncthreads();                        // drains prefetch; next buffer ready
        pb ^= 1;
    }

#pragma unroll
    for (int m = 0; m < 4; m++)
#pragma unroll
        for (int nn = 0; nn < 4; nn++)
#pragma unroll
            for (int r = 0; r < 4; r++) {
                int row = Rb + 64 * wm + 16 * m + 4 * hi + r;
                int col = Cb + 64 * wn + 16 * nn + lo;
                float v = acc[m][nn][r];
                size_t idx = (size_t)row * HIDD + col;
                if (MODE == 0) {
                    float sw = v / (1.0f + expf(-v));
                    float y = sw + normb[idx];
                    Y[idx] = (_Float16)y;
                } else {
                    Out[idx] = v;
                }
            }
}

// ------------------------------------------------------------------------------------
extern "C" void kernel_launch(void* const* d_in, const int* in_sizes, int n_in,
                              void* d_out, int out_size, void* d_ws, size_t ws_size,
                              hipStream_t stream) {
    const float* x   = (const float*)d_in[0];
    const float* wq  = (const float*)d_in[1];
    const float* wk  = (const float*)d_in[2];
    const float* wv  = (const float*)d_in[3];
    const float* w1  = (const float*)d_in[4];
    const float* w2  = (const float*)d_in[5];
    const float* gns = (const float*)d_in[6];
    const float* gnb = (const float*)d_in[7];
    float* out = (float*)d_out;

    // ---- workspace: the proven 64 MiB footprint ----
    char* base = (char*)d_ws;
    size_t off = 0;
    auto carve = [&](size_t bytes) -> void* {
        void* p = base + off;
        off += (bytes + 255) & ~(size_t)255;
        return p;
    };
    _Float16* Qh  = (_Float16*)carve((size_t)BS * HIDD * 2);   // 8 MiB
    _Float16* Ql  = (_Float16*)carve((size_t)BS * HIDD * 2);   // 8 MiB
    _Float16* Kh  = (_Float16*)carve((size_t)BS * HIDD * 2);   // 8 MiB
    _Float16* Kl  = (_Float16*)carve((size_t)BS * HIDD * 2);   // 8 MiB
    _Float16* VTh = (_Float16*)carve((size_t)BS * HIDD * 2);   // 8 MiB
    _Float16* VTl = (_Float16*)carve((size_t)BS * HIDD * 2);   // 8 MiB
    float*    normb = (float*)carve((size_t)BS * HIDD * 4);    // 16 MiB => 64 MiB
    // aliases:
    _Float16* WTh = (_Float16*)normb;                 // 384 KiB (normb written later)
    _Float16* WTl = WTh + (size_t)48 * 4096;          // 384 KiB
    _Float16* xh  = Qh;                               // after k_ret: Q dead
    _Float16* w1t = Kh;                               // after k_ret: K dead
    _Float16* w2t = Kh + (size_t)HIDD * HIDD;
    _Float16* yh  = VTh;                              // after k_ret: VT dead
    // work-queue counter: first 4 B of d_out (overwritten by final GEMM afterwards)
    unsigned* counter = (unsigned*)d_out;
    (void)ws_size; (void)in_sizes; (void)n_in; (void)out_size;

    // 0) weight prep
    k_wprep<<<48, 256, 0, stream>>>(wq, wk, wv, WTh, WTl);
    // 1) projections (V^T written pre-permuted for the PV slot bijection)
    k_proj_mfma<<<dim3(BS / 128, NHH), 512, 0, stream>>>(x, WTh, WTl,
                                                         Qh, Ql, Kh, Kl, VTh, VTl);
    // 2) retention: persistent blocks + work stealing + counted-vmcnt pipeline
    hipMemsetAsync(counter, 0, sizeof(unsigned), stream);
    k_ret_mfma<<<512, 256, 0, stream>>>(Qh, Ql, Kh, Kl, VTh, VTl,
                                        gns, gnb, normb, counter);
    // 3) GEMM operand prep
    k_cvt_h<<<(BS * HIDD) / 4 / 256, 256, 0, stream>>>(x, xh);
    k_tr_h<<<dim3(32, 32), 256, 0, stream>>>(w1, w1t, HIDD, HIDD);
    k_tr_h<<<dim3(32, 32), 256, 0, stream>>>(w2, w2t, HIDD, HIDD);
    // 4) gate GEMM + swish + add norm (double-buffered gload_lds)
    k_gemm_h<0><<<dim3(BS / 128, HIDD / 128), 256, 0, stream>>>(xh, w1t, normb, yh, nullptr);
    // 5) final GEMM -> out f32 (double-buffered gload_lds)
    k_gemm_h<1><<<dim3(BS / 128, HIDD / 128), 256, 0, stream>>>(yh, w2t, nullptr, nullptr, out);
}

// Round 22
// 143.740 us; speedup vs baseline: 1.0465x; 1.0465x over previous
//
#include <hip/hip_runtime.h>

#define HIDD 1024
#define NHH  16
#define HDD  64
#define BBB  2
#define SSS  2048
#define BS   (BBB * SSS)   // 4096

typedef __attribute__((ext_vector_type(8))) _Float16 half8;
typedef __attribute__((ext_vector_type(4))) _Float16 half4;
typedef __attribute__((ext_vector_type(2))) __fp16   fp16x2;
typedef __attribute__((ext_vector_type(4))) float    f32x4;

#define LSCALE 2048.0f        // 2^11: pre-scale for fp16 low part
#define LINV   (1.0f / 2048.0f)

static __device__ __forceinline__ f32x4 mfma16h(half8 a, half8 b, f32x4 c) {
    return __builtin_amdgcn_mfma_f32_16x16x32_f16(a, b, c, 0, 0, 0);
}

// split2 fp16: v ~= h + l*2^-11, rep error ~2^-22 |v|
static __device__ __forceinline__ void split2h(float v, _Float16& h, _Float16& l) {
    h = (_Float16)v;
    l = (_Float16)((v - (float)h) * LSCALE);
}

// async global->LDS, 16B per lane; LDS dest = wave-uniform base + lane*16
static __device__ __forceinline__ void gl_lds16(const _Float16* g, _Float16* l) {
    __builtin_amdgcn_global_load_lds(
        (const __attribute__((address_space(1))) unsigned int*)g,
        (__attribute__((address_space(3))) unsigned int*)l,
        16, 0, 0);
}

// ---------- weight prep: W[n][d][e] f32 -> WT h/l fp16 [mat*16+n][e][d] --------------
__global__ __launch_bounds__(256) void k_wprep(const float* __restrict__ wq,
                                               const float* __restrict__ wk,
                                               const float* __restrict__ wv,
                                               _Float16* __restrict__ WTh,
                                               _Float16* __restrict__ WTl) {
    const int blk = blockIdx.x;            // mat*16 + n
    const int mat = blk >> 4, n = blk & 15;
    const float* src = (mat == 0 ? wq : mat == 1 ? wk : wv) + (size_t)n * 4096;
    for (int c = threadIdx.x; c < 4096; c += 256) {
        int e = c >> 6, d = c & 63;
        float v = src[d * 64 + e];
        _Float16 h, l;
        split2h(v, h, l);
        WTh[(size_t)blk * 4096 + c] = h;   // layout [e][d]
        WTl[(size_t)blk * 4096 + c] = l;
    }
}

// ------- per-head Q/K/V projection: 8 waves/128 rows, all 3 mats staged once ---------
// V^T is written PRE-PERMUTED per 64-t tile: slot s=32kf+8hi+j holds t=32kf+16(j>>2)+4hi+(j&3)
__global__ __launch_bounds__(512) void k_proj_mfma(const float* __restrict__ x,
                                                   const _Float16* __restrict__ WTh,
                                                   const _Float16* __restrict__ WTl,
                                                   _Float16* __restrict__ Qh, _Float16* __restrict__ Ql,
                                                   _Float16* __restrict__ Kh, _Float16* __restrict__ Kl,
                                                   _Float16* __restrict__ VTh, _Float16* __restrict__ VTl) {
    const int n  = blockIdx.y;
    const int R0 = blockIdx.x * 128;
    const int tid = threadIdx.x;
    const int w = tid >> 6, lane = tid & 63;
    const int hi = lane >> 4, lo = lane & 15;

    __shared__ __align__(16) _Float16 smem[27648];

    half8 ah[2], al[2];
#pragma unroll
    for (int kf = 0; kf < 2; kf++) {
        const float* xp = x + (size_t)(R0 + 16 * w + lo) * HIDD + n * HDD + kf * 32 + 8 * hi;
        float4 v0 = *(const float4*)xp;
        float4 v1 = *(const float4*)(xp + 4);
        float vv[8] = { v0.x, v0.y, v0.z, v0.w, v1.x, v1.y, v1.z, v1.w };
#pragma unroll
        for (int j = 0; j < 8; ++j) {
            _Float16 h, l;
            split2h(vv[j], h, l);
            ah[kf][j] = h; al[kf][j] = l;
        }
    }

    for (int c = tid; c < 3072; c += 512) {
        int m = c >> 10, rest = c & 1023, hl = rest >> 9, cc = rest & 511;
        int r = cc >> 3, j8 = (cc & 7) << 3;
        const _Float16* src = (hl ? WTl : WTh) + ((size_t)(m * NHH + n)) * 4096 + r * 64 + j8;
        *(half8*)&smem[(m * 2 + hl) * 4608 + r * 72 + j8] = *(const half8*)src;
    }
    __syncthreads();

    const int bq = R0 >> 11;
    const int sr = R0 & 2047;
    const size_t bn = (size_t)(bq * NHH + n);
    float vkeep[4][4][2];

    for (int mat = 0; mat < 3; ++mat) {
        const _Float16* bh_base = smem + (mat * 2 + 0) * 4608;
        const _Float16* bl_base = smem + (mat * 2 + 1) * 4608;
        f32x4 a0[4], a1[4];
#pragma unroll
        for (int eb = 0; eb < 4; ++eb) {
            a0[eb] = (f32x4){0.f, 0.f, 0.f, 0.f};
            a1[eb] = (f32x4){0.f, 0.f, 0.f, 0.f};
        }
#pragma unroll
        for (int eb = 0; eb < 4; ++eb) {
            half8 bh0 = *(const half8*)&bh_base[(16 * eb + lo) * 72 + 8 * hi];
            half8 bh1 = *(const half8*)&bh_base[(16 * eb + lo) * 72 + 32 + 8 * hi];
            half8 bl0 = *(const half8*)&bl_base[(16 * eb + lo) * 72 + 8 * hi];
            half8 bl1 = *(const half8*)&bl_base[(16 * eb + lo) * 72 + 32 + 8 * hi];
            a0[eb] = mfma16h(ah[0], bh0, a0[eb]);
            a0[eb] = mfma16h(ah[1], bh1, a0[eb]);
            a1[eb] = mfma16h(ah[0], bl0, a1[eb]);
            a1[eb] = mfma16h(al[0], bh0, a1[eb]);
            a1[eb] = mfma16h(ah[1], bl1, a1[eb]);
            a1[eb] = mfma16h(al[1], bh1, a1[eb]);
        }

        if (mat < 2) {
            _Float16* Dh = (mat == 0) ? Qh : Kh;
            _Float16* Dl = (mat == 0) ? Ql : Kl;
#pragma unroll
            for (int eb = 0; eb < 4; ++eb)
#pragma unroll
                for (int r = 0; r < 4; ++r) {
                    int gr = R0 + 16 * w + 4 * hi + r;
                    int s = gr & 2047;
                    float val = a0[eb][r] + a1[eb][r] * LINV;
                    _Float16 h, l;
                    split2h(val, h, l);
                    size_t idx = (bn * SSS + s) * HDD + 16 * eb + lo;
                    Dh[idx] = h; Dl[idx] = l;
                }
        } else {
#pragma unroll
            for (int eb = 0; eb < 4; ++eb)
#pragma unroll
                for (int r = 0; r < 4; ++r) {
                    vkeep[eb][r][0] = a0[eb][r];
                    vkeep[eb][r][1] = a1[eb][r];
                }
        }
    }

    __syncthreads();
    _Float16* tbh = smem;
    _Float16* tbl = smem + 8704;
#pragma unroll
    for (int eb = 0; eb < 4; ++eb)
#pragma unroll
        for (int r = 0; r < 4; ++r) {
            int rl = 16 * w + 4 * hi + r;
            int ch = 16 * eb + lo;
            _Float16 h, l;
            split2h(vkeep[eb][r][0] + vkeep[eb][r][1] * LINV, h, l);
            tbh[ch * 136 + rl] = h;
            tbl[ch * 136 + rl] = l;
        }
    __syncthreads();
    // permuted writeout: dest slot s (within 64-tile) <- src t = a64 + 32kf + 16(j>>2) + 4hi + (j&3)
    for (int c = tid; c < 1024; c += 512) {
        int ch = c >> 4, s8 = (c & 15) << 3;
        int a64 = s8 & 64;
        int s0 = s8 & 63;                              // 32kf + 8hi
        int basePerm = a64 + (s0 & 32) + ((s0 >> 3) & 3) * 4;   // a64 + 32kf + 4hi
        const _Float16* th = &tbh[ch * 136];
        const _Float16* tl = &tbl[ch * 136];
        half4 h0 = *(const half4*)(th + basePerm);
        half4 h1 = *(const half4*)(th + basePerm + 16);
        half4 l0 = *(const half4*)(tl + basePerm);
        half4 l1 = *(const half4*)(tl + basePerm + 16);
        half8 oh = {h0[0], h0[1], h0[2], h0[3], h1[0], h1[1], h1[2], h1[3]};
        half8 ol = {l0[0], l0[1], l0[2], l0[3], l1[0], l1[1], l1[2], l1[3]};
        size_t gi = (bn * HDD + ch) * SSS + sr + s8;
        *(half8*)(VTh + gi) = oh;
        *(half8*)(VTl + gi) = ol;
    }
}

// ---- retention: R18 config (persistent 512 + stealing + dbuf gload_lds) -------------
// ---- packed P-split via v_cvt_pkrtz (fewer VALU ops + pre-packed halves) ------------
__global__ __launch_bounds__(256) void k_ret_mfma(const _Float16* __restrict__ Qh, const _Float16* __restrict__ Ql,
                                                  const _Float16* __restrict__ Kh, const _Float16* __restrict__ Kl,
                                                  const _Float16* __restrict__ VTh, const _Float16* __restrict__ VTl,
                                                  const float* __restrict__ gns,
                                                  const float* __restrict__ gnb,
                                                  float* __restrict__ normb,
                                                  unsigned* __restrict__ counter) {
    const int tid = threadIdx.x;
    const int w = tid >> 6, lane = tid & 63;
    const int hi = lane >> 4, lo = lane & 15;

    // double-buffered sub-tile LDS (linear; swizzle folded into global src)
    __shared__ __align__(16) _Float16 ksh[4096];
    __shared__ __align__(16) _Float16 ksl[4096];
    __shared__ __align__(16) _Float16 vsh[4096];
    __shared__ __align__(16) _Float16 vsl[4096];
    __shared__ unsigned sitem;

    // lane-constant pieces independent of the work item
    const int ks0 = ((hi ^ (lo & 7)) << 3);
    const int ks1 = (((4 + hi) ^ (lo & 7)) << 3);
    const int vs0 = ((hi ^ ((lo >> 1) & 3)) << 3);
    size_t goffK = (size_t)(lane >> 3) * HDD + (size_t)((((lane & 7) ^ ((lane >> 3) & 7))) << 3);
    size_t goffV = (size_t)(lane >> 2) * SSS + (size_t)((((lane & 3) ^ ((lane >> 3) & 3))) << 3);

    const double l512 = -6.2383246250395075;   // log(1/512)
    const double l32  = -3.4657359027997265;   // log(1/32)

    while (true) {
        if (tid == 0) sitem = atomicAdd(counter, 1u);
        __syncthreads();
        const unsigned it = sitem;
        __syncthreads();
        if (it >= 1024u) break;

        // heavy-first decode: qt descending (LPT greedy)
        const int qt = 31 - (int)(it >> 5);
        const int n  = (int)(it & 15);
        const int b  = (int)((it >> 4) & 1);

        double lin = l512 + (double)n * (l32 - l512) / 15.0;
        float gamma = (float)(1.0 - exp(lin));
        float l2g = log2f(gamma);                  // negative
        int dmax = (int)(16.0f / (-l2g)) + 1;      // keep gamma^d >= 2^-16

        const int qb = qt * 64;
        const int qw = qb + 16 * w;
        int stb_start = (qb > dmax) ? ((qb - dmax) >> 5) : 0;
        const int stb_end  = 2 * qt + 1;
        const int stb_diag = qw >> 5;

        const size_t bn = (size_t)(b * NHH + n);
        const _Float16* Qhp = Qh + bn * SSS * HDD;
        const _Float16* Qlp = Ql + bn * SSS * HDD;
        const _Float16* Khp = Kh + bn * SSS * HDD;
        const _Float16* Klp = Kl + bn * SSS * HDD;
        const _Float16* Vhp = VTh + bn * HDD * SSS;
        const _Float16* Vlp = VTl + bn * HDD * SSS;

        half8 qfh[2], qfl[2];
#pragma unroll
        for (int kf = 0; kf < 2; kf++) {
            size_t o = (size_t)(qw + lo) * HDD + kf * 32 + 8 * hi;
            qfh[kf] = *(const half8*)(Qhp + o);
            qfl[kf] = *(const half8*)(Qlp + o);
        }

        f32x4 acc0[4], acc1[4];
#pragma unroll
        for (int e = 0; e < 4; e++) {
            acc0[e] = (f32x4){0.f, 0.f, 0.f, 0.f};
            acc1[e] = (f32x4){0.f, 0.f, 0.f, 0.f};
        }

        const _Float16* sg = (w == 0) ? Khp : (w == 1) ? Klp : (w == 2) ? Vhp : Vlp;
        _Float16* slds = (w == 0) ? ksh : (w == 1) ? ksl : (w == 2) ? vsh : vsl;
        const size_t goff = (w < 2) ? goffK : goffV;

        auto issue = [&](int tbase, int pbuf) {
            _Float16* Lb = slds + pbuf * 2048;
            if (w < 2) {
#pragma unroll
                for (int i = 0; i < 4; ++i)
                    gl_lds16(sg + (size_t)(tbase + 8 * i) * HDD + goff, Lb + i * 512);
            } else {
#pragma unroll
                for (int i = 0; i < 4; ++i)
                    gl_lds16(sg + (size_t)(16 * i) * SSS + tbase + goff, Lb + i * 512);
            }
        };

        float ftile = exp2f((float)(qw + lo - stb_start * 32) * l2g);
        const float gi16   = exp2f(-16.0f * l2g);
        const float ginv32 = exp2f(-32.0f * l2g);
        float f4[4];
#pragma unroll
        for (int r = 0; r < 4; ++r) f4[r] = exp2f(-(float)(4 * hi + r) * l2g);

        int pb = 0;
        issue(stb_start * 32, 0);
        __syncthreads();

        for (int stb = stb_start; stb <= stb_end; ++stb) {
            const int tbase = stb * 32;
            if (stb < stb_end) issue(tbase + 32, pb ^ 1);   // overlap loads with compute

            const bool active = (tbase <= qw + 15) && (tbase + 31 >= qw - dmax);
            if (active) {
                const bool dm = (stb == stb_diag);
                const _Float16* kh_ = &ksh[pb * 2048];
                const _Float16* kl_ = &ksl[pb * 2048];
                const _Float16* vh_ = &vsh[pb * 2048];
                const _Float16* vl_ = &vsl[pb * 2048];
                _Float16 phv[2][4], plv[2][4];
#pragma unroll
                for (int tt = 0; tt < 2; ++tt) {
                    int rb = (16 * tt + lo) * 64;
                    half8 kh0 = *(const half8*)&kh_[rb + ks0];
                    half8 kh1 = *(const half8*)&kh_[rb + ks1];
                    half8 kl0 = *(const half8*)&kl_[rb + ks0];
                    half8 kl1 = *(const half8*)&kl_[rb + ks1];
                    f32x4 s0 = (f32x4){0.f, 0.f, 0.f, 0.f};
                    f32x4 s1 = (f32x4){0.f, 0.f, 0.f, 0.f};
                    s0 = mfma16h(kh0, qfh[0], s0);
                    s0 = mfma16h(kh1, qfh[1], s0);
                    s1 = mfma16h(kl0, qfh[0], s1);
                    s1 = mfma16h(kh0, qfl[0], s1);
                    s1 = mfma16h(kl1, qfh[1], s1);
                    s1 = mfma16h(kh1, qfl[1], s1);
                    const float g = tt ? ftile * gi16 : ftile;
                    float pv[4];
#pragma unroll
                    for (int r = 0; r < 4; r++) {
                        float p = (s0[r] + s1[r] * LINV) * (g * f4[r]);
                        if (dm) {
                            int diff = (qw + lo) - (tbase + 16 * tt + 4 * hi + r);
                            if (diff < 0) p = 0.0f;
                        }
                        pv[r] = p;
                    }
                    // packed split: h via pk-cvt (RTZ), l = (p-h)*2^11 via pk-cvt
                    fp16x2 h01 = __builtin_amdgcn_cvt_pkrtz(pv[0], pv[1]);
                    fp16x2 h23 = __builtin_amdgcn_cvt_pkrtz(pv[2], pv[3]);
                    fp16x2 l01 = __builtin_amdgcn_cvt_pkrtz((pv[0] - (float)h01[0]) * LSCALE,
                                                            (pv[1] - (float)h01[1]) * LSCALE);
                    fp16x2 l23 = __builtin_amdgcn_cvt_pkrtz((pv[2] - (float)h23[0]) * LSCALE,
                                                            (pv[3] - (float)h23[1]) * LSCALE);
                    phv[tt][0] = (_Float16)h01[0]; phv[tt][1] = (_Float16)h01[1];
                    phv[tt][2] = (_Float16)h23[0]; phv[tt][3] = (_Float16)h23[1];
                    plv[tt][0] = (_Float16)l01[0]; plv[tt][1] = (_Float16)l01[1];
                    plv[tt][2] = (_Float16)l23[0]; plv[tt][3] = (_Float16)l23[1];
                }
                half8 pfh = (half8){phv[0][0], phv[0][1], phv[0][2], phv[0][3],
                                    phv[1][0], phv[1][1], phv[1][2], phv[1][3]};
                half8 pfl = (half8){plv[0][0], plv[0][1], plv[0][2], plv[0][3],
                                    plv[1][0], plv[1][1], plv[1][2], plv[1][3]};
#pragma unroll
                for (int e = 0; e < 4; e++) {
                    int vb = (16 * e + lo) * 32 + vs0;
                    half8 vh0 = *(const half8*)&vh_[vb];
                    half8 vl0 = *(const half8*)&vl_[vb];
                    acc0[e] = mfma16h(pfh, vh0, acc0[e]);
                    acc1[e] = mfma16h(pfh, vl0, acc1[e]);
                    acc1[e] = mfma16h(pfl, vh0, acc1[e]);
                }
            }
            ftile *= ginv32;
            __syncthreads();                 // drains gload_lds + syncs LDS reads
            pb ^= 1;
        }

        // combine scaled-low accumulator
        f32x4 accf[4];
#pragma unroll
        for (int e = 0; e < 4; e++)
#pragma unroll
            for (int r = 0; r < 4; r++)
                accf[e][r] = acc0[e][r] + acc1[e][r] * LINV;

        // ---- fused GroupNorm (row=4hi+r -> q, col=lo -> ch; VERIFIED) ----
        float s[4], sq[4];
#pragma unroll
        for (int r = 0; r < 4; r++) {
            s[r] = 0.f; sq[r] = 0.f;
#pragma unroll
            for (int e = 0; e < 4; e++) { float v = accf[e][r]; s[r] += v; sq[r] += v * v; }
        }
#pragma unroll
        for (int mask = 1; mask < 16; mask <<= 1)
#pragma unroll
            for (int r = 0; r < 4; r++) {
                s[r]  += __shfl_xor(s[r],  mask);
                sq[r] += __shfl_xor(sq[r], mask);
            }
#pragma unroll
        for (int e = 0; e < 4; e++)
#pragma unroll
            for (int r = 0; r < 4; r++) {
                float mean = s[r] * (1.0f / 64.0f);
                float var  = sq[r] * (1.0f / 64.0f) - mean * mean;
                float rstd = rsqrtf(var + 1e-5f);
                int ch = 16 * e + lo;
                int sg2 = qw + 4 * hi + r;
                float nv = (accf[e][r] - mean) * rstd;
                nv = nv * gns[n * 64 + ch] + gnb[n * 64 + ch];
                normb[((size_t)b * SSS + sg2) * HIDD + n * 64 + ch] = nv;
            }
        __syncthreads();   // all waves done before next item reuses LDS
    }
}

// ------- fused GEMM operand prep: z=0 cvt x->fp16 ; z=1 w1^T ; z=2 w2^T --------------
__global__ __launch_bounds__(256) void k_prep3(const float* __restrict__ x,
                                               const float* __restrict__ w1,
                                               const float* __restrict__ w2,
                                               _Float16* __restrict__ xh,
                                               _Float16* __restrict__ w1t,
                                               _Float16* __restrict__ w2t) {
    const int z = blockIdx.z;
    if (z == 0) {
        // cast x (4M f32) -> fp16: 1024 blocks x 256 thr x 16 elems
        size_t base = (((size_t)blockIdx.y * 32 + blockIdx.x) * 256 + threadIdx.x) * 16;
#pragma unroll
        for (int j = 0; j < 4; ++j) {
            float4 v = *(const float4*)(x + base + 4 * j);
            half4 o = { (_Float16)v.x, (_Float16)v.y, (_Float16)v.z, (_Float16)v.w };
            *(half4*)(xh + base + 4 * j) = o;
        }
    } else {
        const float* src = (z == 1) ? w1 : w2;
        _Float16* dst = (z == 1) ? w1t : w2t;
        __shared__ float ls[32][33];
        int kb = blockIdx.y * 32, nb = blockIdx.x * 32;
        int tx = threadIdx.x & 31, ty = threadIdx.x >> 5;   // 32 x 8
#pragma unroll
        for (int i = 0; i < 4; i++) {
            int r = ty + 8 * i;
            ls[r][tx] = src[(size_t)(kb + r) * HIDD + nb + tx];
        }
        __syncthreads();
#pragma unroll
        for (int i = 0; i < 4; i++) {
            int r = ty + 8 * i;
            dst[(size_t)(nb + r) * HIDD + kb + tx] = (_Float16)ls[tx][r];
        }
    }
}

// ------- 128x128 fp16 MFMA GEMM, DOUBLE-BUFFERED global_load_lds, BK=64 --------------
template <int MODE>
__global__ __launch_bounds__(256) void k_gemm_h(const _Float16* __restrict__ A,
                                                const _Float16* __restrict__ Bt,
                                                const float* __restrict__ normb,
                                                _Float16* __restrict__ Y,
                                                float* __restrict__ Out) {
    const int Rb = blockIdx.x * 128, Cb = blockIdx.y * 128;
    const int tid = threadIdx.x, w = tid >> 6, lane = tid & 63;
    const int hi = lane >> 4, lo = lane & 15;
    const int wm = w >> 1, wn = w & 1;

    __shared__ __align__(16) _Float16 as[2][128 * 64];   // 2 x 16 KB
    __shared__ __align__(16) _Float16 bs[2][128 * 64];   // 2 x 16 KB

    f32x4 acc[4][4];
#pragma unroll
    for (int m = 0; m < 4; m++)
#pragma unroll
        for (int nn = 0; nn < 4; nn++) acc[m][nn] = (f32x4){0.f, 0.f, 0.f, 0.f};

    const _Float16* gM = (w < 2) ? (A + (size_t)(Rb + 64 * (w & 1)) * HIDD)
                                 : (Bt + (size_t)(Cb + 64 * (w & 1)) * HIDD);
    const int wsel = (w < 2) ? 0 : 1;     // 0 -> as, 1 -> bs
    const size_t gofs = (size_t)(lane >> 3) * HIDD
                      + (size_t)((((lane & 7) ^ ((lane >> 3) & 7))) << 3);

    auto issue = [&](int kk, int pbuf) {
        _Float16* gL = (wsel ? bs[pbuf] : as[pbuf]) + (w & 1) * 64 * 64;
#pragma unroll
        for (int i = 0; i < 8; ++i)
            gl_lds16(gM + (size_t)(8 * i) * HIDD + kk * 64 + gofs, gL + i * 512);
    };

    int rsw[2];
#pragma unroll
    for (int kf = 0; kf < 2; kf++) rsw[kf] = ((4 * kf + hi) ^ (lo & 7)) << 3;

    int pb = 0;
    issue(0, 0);
    __syncthreads();

    for (int kk = 0; kk < 16; ++kk) {
        if (kk < 15) issue(kk + 1, pb ^ 1);     // async loads overlap MFMA below

        half8 af[4][2], bf[4][2];
#pragma unroll
        for (int m = 0; m < 4; m++) {
            int row = 64 * wm + 16 * m + lo;
#pragma unroll
            for (int kf = 0; kf < 2; kf++)
                af[m][kf] = *(const half8*)&as[pb][row * 64 + rsw[kf]];
        }
#pragma unroll
        for (int nn = 0; nn < 4; nn++) {
            int row = 64 * wn + 16 * nn + lo;
#pragma unroll
            for (int kf = 0; kf < 2; kf++)
                bf[nn][kf] = *(const half8*)&bs[pb][row * 64 + rsw[kf]];
        }
#pragma unroll
        for (int m = 0; m < 4; m++)
#pragma unroll
            for (int nn = 0; nn < 4; nn++) {
                acc[m][nn] = mfma16h(af[m][0], bf[nn][0], acc[m][nn]);
                acc[m][nn] = mfma16h(af[m][1], bf[nn][1], acc[m][nn]);
            }
        __syncthreads();                        // drains prefetch; next buffer ready
        pb ^= 1;
    }

#pragma unroll
    for (int m = 0; m < 4; m++)
#pragma unroll
        for (int nn = 0; nn < 4; nn++)
#pragma unroll
            for (int r = 0; r < 4; r++) {
                int row = Rb + 64 * wm + 16 * m + 4 * hi + r;
                int col = Cb + 64 * wn + 16 * nn + lo;
                float v = acc[m][nn][r];
                size_t idx = (size_t)row * HIDD + col;
                if (MODE == 0) {
                    float sw = v / (1.0f + expf(-v));
                    float y = sw + normb[idx];
                    Y[idx] = (_Float16)y;
                } else {
                    Out[idx] = v;
                }
            }
}

// ------------------------------------------------------------------------------------
extern "C" void kernel_launch(void* const* d_in, const int* in_sizes, int n_in,
                              void* d_out, int out_size, void* d_ws, size_t ws_size,
                              hipStream_t stream) {
    const float* x   = (const float*)d_in[0];
    const float* wq  = (const float*)d_in[1];
    const float* wk  = (const float*)d_in[2];
    const float* wv  = (const float*)d_in[3];
    const float* w1  = (const float*)d_in[4];
    const float* w2  = (const float*)d_in[5];
    const float* gns = (const float*)d_in[6];
    const float* gnb = (const float*)d_in[7];
    float* out = (float*)d_out;

    // ---- workspace: the proven 64 MiB footprint ----
    char* base = (char*)d_ws;
    size_t off = 0;
    auto carve = [&](size_t bytes) -> void* {
        void* p = base + off;
        off += (bytes + 255) & ~(size_t)255;
        return p;
    };
    _Float16* Qh  = (_Float16*)carve((size_t)BS * HIDD * 2);   // 8 MiB
    _Float16* Ql  = (_Float16*)carve((size_t)BS * HIDD * 2);   // 8 MiB
    _Float16* Kh  = (_Float16*)carve((size_t)BS * HIDD * 2);   // 8 MiB
    _Float16* Kl  = (_Float16*)carve((size_t)BS * HIDD * 2);   // 8 MiB
    _Float16* VTh = (_Float16*)carve((size_t)BS * HIDD * 2);   // 8 MiB
    _Float16* VTl = (_Float16*)carve((size_t)BS * HIDD * 2);   // 8 MiB
    float*    normb = (float*)carve((size_t)BS * HIDD * 4);    // 16 MiB => 64 MiB
    // aliases:
    _Float16* WTh = (_Float16*)normb;                 // 384 KiB (normb written later)
    _Float16* WTl = WTh + (size_t)48 * 4096;          // 384 KiB
    _Float16* xh  = Qh;                               // after k_ret: Q dead
    _Float16* w1t = Kh;                               // after k_ret: K dead
    _Float16* w2t = Kh + (size_t)HIDD * HIDD;
    _Float16* yh  = VTh;                              // after k_ret: VT dead
    // work-queue counter: first 4 B of d_out (overwritten by final GEMM afterwards)
    unsigned* counter = (unsigned*)d_out;
    (void)ws_size; (void)in_sizes; (void)n_in; (void)out_size;

    // 0) weight prep
    k_wprep<<<48, 256, 0, stream>>>(wq, wk, wv, WTh, WTl);
    // 1) projections (V^T written pre-permuted for the PV slot bijection)
    k_proj_mfma<<<dim3(BS / 128, NHH), 512, 0, stream>>>(x, WTh, WTl,
                                                         Qh, Ql, Kh, Kl, VTh, VTl);
    // 2) retention: persistent blocks + heavy-first work stealing + packed P-split
    (void)hipMemsetAsync(counter, 0, sizeof(unsigned), stream);
    k_ret_mfma<<<512, 256, 0, stream>>>(Qh, Ql, Kh, Kl, VTh, VTl,
                                        gns, gnb, normb, counter);
    // 3) fused GEMM operand prep (cvt + 2 transposes in one launch)
    k_prep3<<<dim3(32, 32, 3), 256, 0, stream>>>(x, w1, w2, xh, w1t, w2t);
    // 4) gate GEMM + swish + add norm (double-buffered gload_lds)
    k_gemm_h<0><<<dim3(BS / 128, HIDD / 128), 256, 0, stream>>>(xh, w1t, normb, yh, nullptr);
    // 5) final GEMM -> out f32 (double-buffered gload_lds)
    k_gemm_h<1><<<dim3(BS / 128, HIDD / 128), 256, 0, stream>>>(yh, w2t, nullptr, nullptr, out);
}

// Round 23
// 135.326 us; speedup vs baseline: 1.1116x; 1.0622x over previous
//
#include <hip/hip_runtime.h>

#define HIDD 1024
#define NHH  16
#define HDD  64
#define BBB  2
#define SSS  2048
#define BS   (BBB * SSS)   // 4096

typedef __attribute__((ext_vector_type(8))) _Float16 half8;
typedef __attribute__((ext_vector_type(4))) _Float16 half4;
typedef __attribute__((ext_vector_type(2))) __fp16   fp16x2;
typedef __attribute__((ext_vector_type(4))) float    f32x4;

#define LSCALE 2048.0f        // 2^11: pre-scale for fp16 low part
#define LINV   (1.0f / 2048.0f)

static __device__ __forceinline__ f32x4 mfma16h(half8 a, half8 b, f32x4 c) {
    return __builtin_amdgcn_mfma_f32_16x16x32_f16(a, b, c, 0, 0, 0);
}

// split2 fp16: v ~= h + l*2^-11, rep error ~2^-22 |v|
static __device__ __forceinline__ void split2h(float v, _Float16& h, _Float16& l) {
    h = (_Float16)v;
    l = (_Float16)((v - (float)h) * LSCALE);
}

// async global->LDS, 16B per lane; LDS dest = wave-uniform base + lane*16
static __device__ __forceinline__ void gl_lds16(const _Float16* g, _Float16* l) {
    __builtin_amdgcn_global_load_lds(
        (const __attribute__((address_space(1))) unsigned int*)g,
        (__attribute__((address_space(3))) unsigned int*)l,
        16, 0, 0);
}

// ---------- weight prep: W[n][d][e] f32 -> WT h/l fp16 [mat*16+n][e][d] --------------
__global__ __launch_bounds__(256) void k_wprep(const float* __restrict__ wq,
                                               const float* __restrict__ wk,
                                               const float* __restrict__ wv,
                                               _Float16* __restrict__ WTh,
                                               _Float16* __restrict__ WTl) {
    const int blk = blockIdx.x;            // mat*16 + n
    const int mat = blk >> 4, n = blk & 15;
    const float* src = (mat == 0 ? wq : mat == 1 ? wk : wv) + (size_t)n * 4096;
    for (int c = threadIdx.x; c < 4096; c += 256) {
        int e = c >> 6, d = c & 63;
        float v = src[d * 64 + e];
        _Float16 h, l;
        split2h(v, h, l);
        WTh[(size_t)blk * 4096 + c] = h;   // layout [e][d]
        WTl[(size_t)blk * 4096 + c] = l;
    }
}

// ------- per-head Q/K/V projection: 8 waves/128 rows, all 3 mats staged once ---------
// V^T is written PRE-PERMUTED per 64-t tile: slot s=32kf+8hi+j holds t=32kf+16(j>>2)+4hi+(j&3)
__global__ __launch_bounds__(512) void k_proj_mfma(const float* __restrict__ x,
                                                   const _Float16* __restrict__ WTh,
                                                   const _Float16* __restrict__ WTl,
                                                   _Float16* __restrict__ Qh, _Float16* __restrict__ Ql,
                                                   _Float16* __restrict__ Kh, _Float16* __restrict__ Kl,
                                                   _Float16* __restrict__ VTh, _Float16* __restrict__ VTl) {
    const int n  = blockIdx.y;
    const int R0 = blockIdx.x * 128;
    const int tid = threadIdx.x;
    const int w = tid >> 6, lane = tid & 63;
    const int hi = lane >> 4, lo = lane & 15;

    __shared__ __align__(16) _Float16 smem[27648];

    half8 ah[2], al[2];
#pragma unroll
    for (int kf = 0; kf < 2; kf++) {
        const float* xp = x + (size_t)(R0 + 16 * w + lo) * HIDD + n * HDD + kf * 32 + 8 * hi;
        float4 v0 = *(const float4*)xp;
        float4 v1 = *(const float4*)(xp + 4);
        float vv[8] = { v0.x, v0.y, v0.z, v0.w, v1.x, v1.y, v1.z, v1.w };
#pragma unroll
        for (int j = 0; j < 8; ++j) {
            _Float16 h, l;
            split2h(vv[j], h, l);
            ah[kf][j] = h; al[kf][j] = l;
        }
    }

    for (int c = tid; c < 3072; c += 512) {
        int m = c >> 10, rest = c & 1023, hl = rest >> 9, cc = rest & 511;
        int r = cc >> 3, j8 = (cc & 7) << 3;
        const _Float16* src = (hl ? WTl : WTh) + ((size_t)(m * NHH + n)) * 4096 + r * 64 + j8;
        *(half8*)&smem[(m * 2 + hl) * 4608 + r * 72 + j8] = *(const half8*)src;
    }
    __syncthreads();

    const int bq = R0 >> 11;
    const int sr = R0 & 2047;
    const size_t bn = (size_t)(bq * NHH + n);
    float vkeep[4][4][2];

    for (int mat = 0; mat < 3; ++mat) {
        const _Float16* bh_base = smem + (mat * 2 + 0) * 4608;
        const _Float16* bl_base = smem + (mat * 2 + 1) * 4608;
        f32x4 a0[4], a1[4];
#pragma unroll
        for (int eb = 0; eb < 4; ++eb) {
            a0[eb] = (f32x4){0.f, 0.f, 0.f, 0.f};
            a1[eb] = (f32x4){0.f, 0.f, 0.f, 0.f};
        }
#pragma unroll
        for (int eb = 0; eb < 4; ++eb) {
            half8 bh0 = *(const half8*)&bh_base[(16 * eb + lo) * 72 + 8 * hi];
            half8 bh1 = *(const half8*)&bh_base[(16 * eb + lo) * 72 + 32 + 8 * hi];
            half8 bl0 = *(const half8*)&bl_base[(16 * eb + lo) * 72 + 8 * hi];
            half8 bl1 = *(const half8*)&bl_base[(16 * eb + lo) * 72 + 32 + 8 * hi];
            a0[eb] = mfma16h(ah[0], bh0, a0[eb]);
            a0[eb] = mfma16h(ah[1], bh1, a0[eb]);
            a1[eb] = mfma16h(ah[0], bl0, a1[eb]);
            a1[eb] = mfma16h(al[0], bh0, a1[eb]);
            a1[eb] = mfma16h(ah[1], bl1, a1[eb]);
            a1[eb] = mfma16h(al[1], bh1, a1[eb]);
        }

        if (mat < 2) {
            _Float16* Dh = (mat == 0) ? Qh : Kh;
            _Float16* Dl = (mat == 0) ? Ql : Kl;
#pragma unroll
            for (int eb = 0; eb < 4; ++eb)
#pragma unroll
                for (int r = 0; r < 4; ++r) {
                    int gr = R0 + 16 * w + 4 * hi + r;
                    int s = gr & 2047;
                    float val = a0[eb][r] + a1[eb][r] * LINV;
                    _Float16 h, l;
                    split2h(val, h, l);
                    size_t idx = (bn * SSS + s) * HDD + 16 * eb + lo;
                    Dh[idx] = h; Dl[idx] = l;
                }
        } else {
#pragma unroll
            for (int eb = 0; eb < 4; ++eb)
#pragma unroll
                for (int r = 0; r < 4; ++r) {
                    vkeep[eb][r][0] = a0[eb][r];
                    vkeep[eb][r][1] = a1[eb][r];
                }
        }
    }

    __syncthreads();
    _Float16* tbh = smem;
    _Float16* tbl = smem + 8704;
#pragma unroll
    for (int eb = 0; eb < 4; ++eb)
#pragma unroll
        for (int r = 0; r < 4; ++r) {
            int rl = 16 * w + 4 * hi + r;
            int ch = 16 * eb + lo;
            _Float16 h, l;
            split2h(vkeep[eb][r][0] + vkeep[eb][r][1] * LINV, h, l);
            tbh[ch * 136 + rl] = h;
            tbl[ch * 136 + rl] = l;
        }
    __syncthreads();
    // permuted writeout: dest slot s (within 64-tile) <- src t = a64 + 32kf + 16(j>>2) + 4hi + (j&3)
    for (int c = tid; c < 1024; c += 512) {
        int ch = c >> 4, s8 = (c & 15) << 3;
        int a64 = s8 & 64;
        int s0 = s8 & 63;                              // 32kf + 8hi
        int basePerm = a64 + (s0 & 32) + ((s0 >> 3) & 3) * 4;   // a64 + 32kf + 4hi
        const _Float16* th = &tbh[ch * 136];
        const _Float16* tl = &tbl[ch * 136];
        half4 h0 = *(const half4*)(th + basePerm);
        half4 h1 = *(const half4*)(th + basePerm + 16);
        half4 l0 = *(const half4*)(tl + basePerm);
        half4 l1 = *(const half4*)(tl + basePerm + 16);
        half8 oh = {h0[0], h0[1], h0[2], h0[3], h1[0], h1[1], h1[2], h1[3]};
        half8 ol = {l0[0], l0[1], l0[2], l0[3], l1[0], l1[1], l1[2], l1[3]};
        size_t gi = (bn * HDD + ch) * SSS + sr + s8;
        *(half8*)(VTh + gi) = oh;
        *(half8*)(VTl + gi) = ol;
    }
}

// ---- retention: persistent 512 + stealing + 4-buffer LDS, ONE barrier per 2 subtiles
__global__ __launch_bounds__(256) void k_ret_mfma(const _Float16* __restrict__ Qh, const _Float16* __restrict__ Ql,
                                                  const _Float16* __restrict__ Kh, const _Float16* __restrict__ Kl,
                                                  const _Float16* __restrict__ VTh, const _Float16* __restrict__ VTl,
                                                  const float* __restrict__ gns,
                                                  const float* __restrict__ gnb,
                                                  float* __restrict__ normb,
                                                  unsigned* __restrict__ counter) {
    const int tid = threadIdx.x;
    const int w = tid >> 6, lane = tid & 63;
    const int hi = lane >> 4, lo = lane & 15;

    // 4 sub-tile buffers per array (16 KB each, 64 KB total)
    __shared__ __align__(16) _Float16 ksh[8192];
    __shared__ __align__(16) _Float16 ksl[8192];
    __shared__ __align__(16) _Float16 vsh[8192];
    __shared__ __align__(16) _Float16 vsl[8192];
    __shared__ unsigned sitem;

    // lane-constant pieces independent of the work item
    const int ks0 = ((hi ^ (lo & 7)) << 3);
    const int ks1 = (((4 + hi) ^ (lo & 7)) << 3);
    const int vs0 = ((hi ^ ((lo >> 1) & 3)) << 3);
    size_t goffK = (size_t)(lane >> 3) * HDD + (size_t)((((lane & 7) ^ ((lane >> 3) & 7))) << 3);
    size_t goffV = (size_t)(lane >> 2) * SSS + (size_t)((((lane & 3) ^ ((lane >> 3) & 3))) << 3);

    const double l512 = -6.2383246250395075;   // log(1/512)
    const double l32  = -3.4657359027997265;   // log(1/32)

    while (true) {
        if (tid == 0) sitem = atomicAdd(counter, 1u);
        __syncthreads();
        const unsigned it = sitem;
        __syncthreads();
        if (it >= 1024u) break;

        // heavy-first decode: qt descending (LPT greedy)
        const int qt = 31 - (int)(it >> 5);
        const int n  = (int)(it & 15);
        const int b  = (int)((it >> 4) & 1);

        double lin = l512 + (double)n * (l32 - l512) / 15.0;
        float gamma = (float)(1.0 - exp(lin));
        float l2g = log2f(gamma);                  // negative
        int dmax = (int)(16.0f / (-l2g)) + 1;      // keep gamma^d >= 2^-16

        const int qb = qt * 64;
        const int qw = qb + 16 * w;
        int stb_start = (qb > dmax) ? ((qb - dmax) >> 5) : 0;
        const int stb_end  = 2 * qt + 1;
        const int stb_diag = qw >> 5;

        const size_t bn = (size_t)(b * NHH + n);
        const _Float16* Qhp = Qh + bn * SSS * HDD;
        const _Float16* Qlp = Ql + bn * SSS * HDD;
        const _Float16* Khp = Kh + bn * SSS * HDD;
        const _Float16* Klp = Kl + bn * SSS * HDD;
        const _Float16* Vhp = VTh + bn * HDD * SSS;
        const _Float16* Vlp = VTl + bn * HDD * SSS;

        half8 qfh[2], qfl[2];
#pragma unroll
        for (int kf = 0; kf < 2; kf++) {
            size_t o = (size_t)(qw + lo) * HDD + kf * 32 + 8 * hi;
            qfh[kf] = *(const half8*)(Qhp + o);
            qfl[kf] = *(const half8*)(Qlp + o);
        }

        f32x4 acc0[4], acc1[4];
#pragma unroll
        for (int e = 0; e < 4; e++) {
            acc0[e] = (f32x4){0.f, 0.f, 0.f, 0.f};
            acc1[e] = (f32x4){0.f, 0.f, 0.f, 0.f};
        }

        // per-item, lane-folded staging base pointers
        const _Float16* sg = (w == 0) ? (Khp + goffK) : (w == 1) ? (Klp + goffK)
                           : (w == 2) ? (Vhp + goffV) : (Vlp + goffV);
        _Float16* slds = (w == 0) ? ksh : (w == 1) ? ksl : (w == 2) ? vsh : vsl;
        const bool isK = (w < 2);

        auto issue = [&](int tbase, int pbuf) {
            _Float16* Lb = slds + pbuf * 2048;
            if (isK) {
                const _Float16* gp = sg + (size_t)tbase * HDD;
#pragma unroll
                for (int i = 0; i < 4; ++i)
                    gl_lds16(gp + (size_t)(8 * i) * HDD, Lb + i * 512);
            } else {
                const _Float16* gp = sg + tbase;
#pragma unroll
                for (int i = 0; i < 4; ++i)
                    gl_lds16(gp + (size_t)(16 * i) * SSS, Lb + i * 512);
            }
        };

        float ftile = exp2f((float)(qw + lo - stb_start * 32) * l2g);
        const float gi16   = exp2f(-16.0f * l2g);
        const float ginv32 = exp2f(-32.0f * l2g);
        float f4[4];
#pragma unroll
        for (int r = 0; r < 4; ++r) f4[r] = exp2f(-(float)(4 * hi + r) * l2g);

        // one subtile's compute (reads buffer bi; no barrier inside)
        auto work = [&](int stb, int bi) {
            const int tbase = stb * 32;
            const bool active = (tbase <= qw + 15) && (tbase + 31 >= qw - dmax);
            if (active) {
                const bool dm = (stb == stb_diag);
                const _Float16* kh_ = &ksh[bi * 2048];
                const _Float16* kl_ = &ksl[bi * 2048];
                const _Float16* vh_ = &vsh[bi * 2048];
                const _Float16* vl_ = &vsl[bi * 2048];
                _Float16 phv[2][4], plv[2][4];
#pragma unroll
                for (int tt = 0; tt < 2; ++tt) {
                    int rb = (16 * tt + lo) * 64;
                    half8 kh0 = *(const half8*)&kh_[rb + ks0];
                    half8 kh1 = *(const half8*)&kh_[rb + ks1];
                    half8 kl0 = *(const half8*)&kl_[rb + ks0];
                    half8 kl1 = *(const half8*)&kl_[rb + ks1];
                    f32x4 s0 = (f32x4){0.f, 0.f, 0.f, 0.f};
                    f32x4 s1 = (f32x4){0.f, 0.f, 0.f, 0.f};
                    s0 = mfma16h(kh0, qfh[0], s0);
                    s0 = mfma16h(kh1, qfh[1], s0);
                    s1 = mfma16h(kl0, qfh[0], s1);
                    s1 = mfma16h(kh0, qfl[0], s1);
                    s1 = mfma16h(kl1, qfh[1], s1);
                    s1 = mfma16h(kh1, qfl[1], s1);
                    const float g = tt ? ftile * gi16 : ftile;
                    float pv[4];
#pragma unroll
                    for (int r = 0; r < 4; r++) {
                        float p = (s0[r] + s1[r] * LINV) * (g * f4[r]);
                        if (dm) {
                            int diff = (qw + lo) - (tbase + 16 * tt + 4 * hi + r);
                            if (diff < 0) p = 0.0f;
                        }
                        pv[r] = p;
                    }
                    fp16x2 h01 = __builtin_amdgcn_cvt_pkrtz(pv[0], pv[1]);
                    fp16x2 h23 = __builtin_amdgcn_cvt_pkrtz(pv[2], pv[3]);
                    fp16x2 l01 = __builtin_amdgcn_cvt_pkrtz((pv[0] - (float)h01[0]) * LSCALE,
                                                            (pv[1] - (float)h01[1]) * LSCALE);
                    fp16x2 l23 = __builtin_amdgcn_cvt_pkrtz((pv[2] - (float)h23[0]) * LSCALE,
                                                            (pv[3] - (float)h23[1]) * LSCALE);
                    phv[tt][0] = (_Float16)h01[0]; phv[tt][1] = (_Float16)h01[1];
                    phv[tt][2] = (_Float16)h23[0]; phv[tt][3] = (_Float16)h23[1];
                    plv[tt][0] = (_Float16)l01[0]; plv[tt][1] = (_Float16)l01[1];
                    plv[tt][2] = (_Float16)l23[0]; plv[tt][3] = (_Float16)l23[1];
                }
                half8 pfh = (half8){phv[0][0], phv[0][1], phv[0][2], phv[0][3],
                                    phv[1][0], phv[1][1], phv[1][2], phv[1][3]};
                half8 pfl = (half8){plv[0][0], plv[0][1], plv[0][2], plv[0][3],
                                    plv[1][0], plv[1][1], plv[1][2], plv[1][3]};
#pragma unroll
                for (int e = 0; e < 4; e++) {
                    int vb = (16 * e + lo) * 32 + vs0;
                    half8 vh0 = *(const half8*)&vh_[vb];
                    half8 vl0 = *(const half8*)&vl_[vb];
                    acc0[e] = mfma16h(pfh, vh0, acc0[e]);
                    acc1[e] = mfma16h(pfh, vl0, acc1[e]);
                    acc1[e] = mfma16h(pfl, vh0, acc1[e]);
                }
            }
            ftile *= ginv32;
        };

        // prologue: first pair in flight
        issue(stb_start * 32, 0);
        if (stb_start + 1 <= stb_end) issue(stb_start * 32 + 32, 1);
        __syncthreads();

        for (int stb = stb_start; stb <= stb_end; stb += 2) {
            const int bi = (stb - stb_start) & 3;
            if (stb + 2 <= stb_end) issue((stb + 2) * 32, (bi + 2) & 3);
            if (stb + 3 <= stb_end) issue((stb + 3) * 32, (bi + 3) & 3);

            work(stb, bi);
            if (stb + 1 <= stb_end) work(stb + 1, (bi + 1) & 3);
            __syncthreads();            // drains prefetch + syncs reads (1 per 2 subtiles)
        }

        // combine scaled-low accumulator
        f32x4 accf[4];
#pragma unroll
        for (int e = 0; e < 4; e++)
#pragma unroll
            for (int r = 0; r < 4; r++)
                accf[e][r] = acc0[e][r] + acc1[e][r] * LINV;

        // ---- fused GroupNorm (row=4hi+r -> q, col=lo -> ch; VERIFIED) ----
        float s[4], sq[4];
#pragma unroll
        for (int r = 0; r < 4; r++) {
            s[r] = 0.f; sq[r] = 0.f;
#pragma unroll
            for (int e = 0; e < 4; e++) { float v = accf[e][r]; s[r] += v; sq[r] += v * v; }
        }
#pragma unroll
        for (int mask = 1; mask < 16; mask <<= 1)
#pragma unroll
            for (int r = 0; r < 4; r++) {
                s[r]  += __shfl_xor(s[r],  mask);
                sq[r] += __shfl_xor(sq[r], mask);
            }
#pragma unroll
        for (int e = 0; e < 4; e++)
#pragma unroll
            for (int r = 0; r < 4; r++) {
                float mean = s[r] * (1.0f / 64.0f);
                float var  = sq[r] * (1.0f / 64.0f) - mean * mean;
                float rstd = rsqrtf(var + 1e-5f);
                int ch = 16 * e + lo;
                int sg2 = qw + 4 * hi + r;
                float nv = (accf[e][r] - mean) * rstd;
                nv = nv * gns[n * 64 + ch] + gnb[n * 64 + ch];
                normb[((size_t)b * SSS + sg2) * HIDD + n * 64 + ch] = nv;
            }
        __syncthreads();   // all waves done before next item reuses LDS
    }
}

// ------- fused GEMM operand prep: z=0 cvt x->fp16 ; z=1 w1^T ; z=2 w2^T --------------
__global__ __launch_bounds__(256) void k_prep3(const float* __restrict__ x,
                                               const float* __restrict__ w1,
                                               const float* __restrict__ w2,
                                               _Float16* __restrict__ xh,
                                               _Float16* __restrict__ w1t,
                                               _Float16* __restrict__ w2t) {
    const int z = blockIdx.z;
    if (z == 0) {
        // cast x (4M f32) -> fp16: 1024 blocks x 256 thr x 16 elems
        size_t base = (((size_t)blockIdx.y * 32 + blockIdx.x) * 256 + threadIdx.x) * 16;
#pragma unroll
        for (int j = 0; j < 4; ++j) {
            float4 v = *(const float4*)(x + base + 4 * j);
            half4 o = { (_Float16)v.x, (_Float16)v.y, (_Float16)v.z, (_Float16)v.w };
            *(half4*)(xh + base + 4 * j) = o;
        }
    } else {
        const float* src = (z == 1) ? w1 : w2;
        _Float16* dst = (z == 1) ? w1t : w2t;
        __shared__ float ls[32][33];
        int kb = blockIdx.y * 32, nb = blockIdx.x * 32;
        int tx = threadIdx.x & 31, ty = threadIdx.x >> 5;   // 32 x 8
#pragma unroll
        for (int i = 0; i < 4; i++) {
            int r = ty + 8 * i;
            ls[r][tx] = src[(size_t)(kb + r) * HIDD + nb + tx];
        }
        __syncthreads();
#pragma unroll
        for (int i = 0; i < 4; i++) {
            int r = ty + 8 * i;
            dst[(size_t)(nb + r) * HIDD + kb + tx] = (_Float16)ls[tx][r];
        }
    }
}

// ------- 128x128 fp16 MFMA GEMM, DOUBLE-BUFFERED global_load_lds, BK=64 --------------
template <int MODE>
__global__ __launch_bounds__(256) void k_gemm_h(const _Float16* __restrict__ A,
                                                const _Float16* __restrict__ Bt,
                                                const float* __restrict__ normb,
                                                _Float16* __restrict__ Y,
                                                float* __restrict__ Out) {
    const int Rb = blockIdx.x * 128, Cb = blockIdx.y * 128;
    const int tid = threadIdx.x, w = tid >> 6, lane = tid & 63;
    const int hi = lane >> 4, lo = lane & 15;
    const int wm = w >> 1, wn = w & 1;

    __shared__ __align__(16) _Float16 as[2][128 * 64];   // 2 x 16 KB
    __shared__ __align__(16) _Float16 bs[2][128 * 64];   // 2 x 16 KB

    f32x4 acc[4][4];
#pragma unroll
    for (int m = 0; m < 4; m++)
#pragma unroll
        for (int nn = 0; nn < 4; nn++) acc[m][nn] = (f32x4){0.f, 0.f, 0.f, 0.f};

    const _Float16* gM = (w < 2) ? (A + (size_t)(Rb + 64 * (w & 1)) * HIDD)
                                 : (Bt + (size_t)(Cb + 64 * (w & 1)) * HIDD);
    const int wsel = (w < 2) ? 0 : 1;     // 0 -> as, 1 -> bs
    const size_t gofs = (size_t)(lane >> 3) * HIDD
                      + (size_t)((((lane & 7) ^ ((lane >> 3) & 7))) << 3);

    auto issue = [&](int kk, int pbuf) {
        _Float16* gL = (wsel ? bs[pbuf] : as[pbuf]) + (w & 1) * 64 * 64;
#pragma unroll
        for (int i = 0; i < 8; ++i)
            gl_lds16(gM + (size_t)(8 * i) * HIDD + kk * 64 + gofs, gL + i * 512);
    };

    int rsw[2];
#pragma unroll
    for (int kf = 0; kf < 2; kf++) rsw[kf] = ((4 * kf + hi) ^ (lo & 7)) << 3;

    int pb = 0;
    issue(0, 0);
    __syncthreads();

    for (int kk = 0; kk < 16; ++kk) {
        if (kk < 15) issue(kk + 1, pb ^ 1);     // async loads overlap MFMA below

        half8 af[4][2], bf[4][2];
#pragma unroll
        for (int m = 0; m < 4; m++) {
            int row = 64 * wm + 16 * m + lo;
#pragma unroll
            for (int kf = 0; kf < 2; kf++)
                af[m][kf] = *(const half8*)&as[pb][row * 64 + rsw[kf]];
        }
#pragma unroll
        for (int nn = 0; nn < 4; nn++) {
            int row = 64 * wn + 16 * nn + lo;
#pragma unroll
            for (int kf = 0; kf < 2; kf++)
                bf[nn][kf] = *(const half8*)&bs[pb][row * 64 + rsw[kf]];
        }
#pragma unroll
        for (int m = 0; m < 4; m++)
#pragma unroll
            for (int nn = 0; nn < 4; nn++) {
                acc[m][nn] = mfma16h(af[m][0], bf[nn][0], acc[m][nn]);
                acc[m][nn] = mfma16h(af[m][1], bf[nn][1], acc[m][nn]);
            }
        __syncthreads();                        // drains prefetch; next buffer ready
        pb ^= 1;
    }

#pragma unroll
    for (int m = 0; m < 4; m++)
#pragma unroll
        for (int nn = 0; nn < 4; nn++)
#pragma unroll
            for (int r = 0; r < 4; r++) {
                int row = Rb + 64 * wm + 16 * m + 4 * hi + r;
                int col = Cb + 64 * wn + 16 * nn + lo;
                float v = acc[m][nn][r];
                size_t idx = (size_t)row * HIDD + col;
                if (MODE == 0) {
                    float sw = v / (1.0f + expf(-v));
                    float y = sw + normb[idx];
                    Y[idx] = (_Float16)y;
                } else {
                    Out[idx] = v;
                }
            }
}

// ------------------------------------------------------------------------------------
extern "C" void kernel_launch(void* const* d_in, const int* in_sizes, int n_in,
                              void* d_out, int out_size, void* d_ws, size_t ws_size,
                              hipStream_t stream) {
    const float* x   = (const float*)d_in[0];
    const float* wq  = (const float*)d_in[1];
    const float* wk  = (const float*)d_in[2];
    const float* wv  = (const float*)d_in[3];
    const float* w1  = (const float*)d_in[4];
    const float* w2  = (const float*)d_in[5];
    const float* gns = (const float*)d_in[6];
    const float* gnb = (const float*)d_in[7];
    float* out = (float*)d_out;

    // ---- workspace: the proven 64 MiB footprint ----
    char* base = (char*)d_ws;
    size_t off = 0;
    auto carve = [&](size_t bytes) -> void* {
        void* p = base + off;
        off += (bytes + 255) & ~(size_t)255;
        return p;
    };
    _Float16* Qh  = (_Float16*)carve((size_t)BS * HIDD * 2);   // 8 MiB
    _Float16* Ql  = (_Float16*)carve((size_t)BS * HIDD * 2);   // 8 MiB
    _Float16* Kh  = (_Float16*)carve((size_t)BS * HIDD * 2);   // 8 MiB
    _Float16* Kl  = (_Float16*)carve((size_t)BS * HIDD * 2);   // 8 MiB
    _Float16* VTh = (_Float16*)carve((size_t)BS * HIDD * 2);   // 8 MiB
    _Float16* VTl = (_Float16*)carve((size_t)BS * HIDD * 2);   // 8 MiB
    float*    normb = (float*)carve((size_t)BS * HIDD * 4);    // 16 MiB => 64 MiB
    // aliases:
    _Float16* WTh = (_Float16*)normb;                 // 384 KiB (normb written later)
    _Float16* WTl = WTh + (size_t)48 * 4096;          // 384 KiB
    _Float16* xh  = Qh;                               // after k_ret: Q dead
    _Float16* w1t = Kh;                               // after k_ret: K dead
    _Float16* w2t = Kh + (size_t)HIDD * HIDD;
    _Float16* yh  = VTh;                              // after k_ret: VT dead
    // work-queue counter: first 4 B of d_out (overwritten by final GEMM afterwards)
    unsigned* counter = (unsigned*)d_out;
    (void)ws_size; (void)in_sizes; (void)n_in; (void)out_size;

    // 0) weight prep
    k_wprep<<<48, 256, 0, stream>>>(wq, wk, wv, WTh, WTl);
    // 1) projections (V^T written pre-permuted for the PV slot bijection)
    k_proj_mfma<<<dim3(BS / 128, NHH), 512, 0, stream>>>(x, WTh, WTl,
                                                         Qh, Ql, Kh, Kl, VTh, VTl);
    // 2) retention: persistent blocks + work stealing + 2-subtile barrier period
    (void)hipMemsetAsync(counter, 0, sizeof(unsigned), stream);
    k_ret_mfma<<<512, 256, 0, stream>>>(Qh, Ql, Kh, Kl, VTh, VTl,
                                        gns, gnb, normb, counter);
    // 3) fused GEMM operand prep (cvt + 2 transposes in one launch)
    k_prep3<<<dim3(32, 32, 3), 256, 0, stream>>>(x, w1, w2, xh, w1t, w2t);
    // 4) gate GEMM + swish + add norm (double-buffered gload_lds)
    k_gemm_h<0><<<dim3(BS / 128, HIDD / 128), 256, 0, stream>>>(xh, w1t, normb, yh, nullptr);
    // 5) final GEMM -> out f32 (double-buffered gload_lds)
    k_gemm_h<1><<<dim3(BS / 128, HIDD / 128), 256, 0, stream>>>(yh, w2t, nullptr, nullptr, out);
}